// Round 9
// baseline (262.948 us; speedup 1.0000x reference)
//
#include <hip/hip_runtime.h>
#include <hip/hip_bf16.h>
#include <math.h>

// Problem constants
#define T_LEN   4096
#define D_DIM   512
#define H_NUM   8
#define HD_DIM  64
#define W_WIN   32
#define HID_DIM 1536
#define M_ROWS  8192   // B*T
#define QKV_LD  1536   // fused q|kv row stride
#define BK 64

typedef __hip_bfloat16 bf16;
typedef __bf16  bf16x8 __attribute__((ext_vector_type(8)));
typedef __bf16  bf16x4 __attribute__((ext_vector_type(4)));
typedef float   f32x4  __attribute__((ext_vector_type(4)));

#define G_AS __attribute__((address_space(1)))
#define L_AS __attribute__((address_space(3)))

#define SBAR()        __builtin_amdgcn_s_barrier()
#define SCHED_FENCE() __builtin_amdgcn_sched_barrier(0)
#define WAIT_VM(N)    asm volatile("s_waitcnt vmcnt(" #N ")" ::: "memory")
#define WAIT_LGKM0()  asm volatile("s_waitcnt lgkmcnt(0)" ::: "memory")

__device__ __forceinline__ float b2f(bf16 x) { return __bfloat162float(x); }
__device__ __forceinline__ bf16  f2b(float x){ return __float2bfloat16(x); }

// 16B async global->LDS DMA (gfx950). Dest must be linear: base + lane*16.
__device__ __forceinline__ void gload_lds16(const bf16* g, bf16* l) {
  __builtin_amdgcn_global_load_lds((const G_AS unsigned int*)g,
                                   (L_AS unsigned int*)l, 16, 0, 0);
}

__device__ __forceinline__ float rdP(const void* p, int i, bool f32) {
  return f32 ? ((const float*)p)[i] : b2f(((const bf16*)p)[i]);
}

__device__ __forceinline__ float wave_reduce_sum(float v) {
  #pragma unroll
  for (int off = 32; off; off >>= 1) v += __shfl_xor(v, off, 64);
  return v;
}

// Wave-parallel dtype detection over a fixed 256 dwords of x (deterministic).
__device__ __forceinline__ bool detect_f32(const unsigned* __restrict__ x) {
  int lane = threadIdx.x & 63;
  int votes = 0;
  #pragma unroll
  for (int i = 0; i < 4; ++i) {
    unsigned e = (x[lane * 4 + i] >> 7) & 0xffu;
    votes += (e >= 90u && e <= 140u) ? 1 : 0;
  }
  float v = wave_reduce_sum((float)votes);
  return v < 200.f;
}

// XCD-aware 1-D block swizzle (R8-validated): lid%8 = XCD; same-by tiles
// land on one XCD so the A row-panel is fetched into exactly one L2.
// All grids used are multiples of 8 -> bijective.
__device__ __forceinline__ void swizzle_xy(int gx, int& bx, int& by) {
  int lid = blockIdx.x;
  int sub = lid & 7;
  int grp = lid >> 3;
  bx = grp % gx;
  by = (grp / gx) * 8 + sub;
}

// ---------------------------------------------------------------------------
// LayerNorm (R2-validated numerics; self-detecting dtype).
// ---------------------------------------------------------------------------
__global__ __launch_bounds__(256) void ln_kernel(
    const void* __restrict__ in, const void* __restrict__ g, const void* __restrict__ bb,
    void* __restrict__ out, int mode,
    const void* __restrict__ freqs, const void* __restrict__ phases,
    const void* __restrict__ amp,
    const unsigned* __restrict__ xdet, int in_follows, int out_follows)
{
  bool f32  = detect_f32(xdet);
  bool inF  = f32 && (in_follows != 0);
  bool outF = f32 && (out_follows != 0);

  int wave = threadIdx.x >> 6;
  int lane = threadIdx.x & 63;
  int row  = blockIdx.x * 4 + wave;

  float x[8];
  if (inF) {
    const float* rp = (const float*)in + (size_t)row * D_DIM + lane * 8;
    float4 v0 = *reinterpret_cast<const float4*>(rp);
    float4 v1 = *reinterpret_cast<const float4*>(rp + 4);
    x[0]=v0.x; x[1]=v0.y; x[2]=v0.z; x[3]=v0.w;
    x[4]=v1.x; x[5]=v1.y; x[6]=v1.z; x[7]=v1.w;
  } else {
    bf16x8 v = *reinterpret_cast<const bf16x8*>(
        (const bf16*)in + (size_t)row * D_DIM + lane * 8);
    #pragma unroll
    for (int i = 0; i < 8; ++i) x[i] = (float)v[i];
  }

  float s = 0.f, s2 = 0.f;
  #pragma unroll
  for (int i = 0; i < 8; ++i) { s += x[i]; s2 += x[i]*x[i]; }
  s  = wave_reduce_sum(s);
  s2 = wave_reduce_sum(s2);
  float mu   = s * (1.f / D_DIM);
  float var  = s2 * (1.f / D_DIM) - mu * mu;
  float rstd = rsqrtf(var + 1e-5f);

  int t = row & (T_LEN - 1);
  float ampf = (mode == 1) ? rdP(amp, 0, f32) : 0.f;

  float o[8];
  #pragma unroll
  for (int i = 0; i < 8; ++i) {
    int d = lane * 8 + i;
    float val = (x[i] - mu) * rstd * rdP(g, d, f32) + rdP(bb, d, f32);
    if (mode == 1) {
      float m = __sinf(fmaf((float)t, rdP(freqs, d, f32), rdP(phases, d, f32)));
      val *= (1.f + ampf * m);
    }
    o[i] = val;
  }

  if (outF) {
    float* op = (float*)out + (size_t)row * D_DIM + lane * 8;
    *reinterpret_cast<float4*>(op)     = make_float4(o[0], o[1], o[2], o[3]);
    *reinterpret_cast<float4*>(op + 4) = make_float4(o[4], o[5], o[6], o[7]);
  } else {
    bf16x8 ov;
    #pragma unroll
    for (int i = 0; i < 8; ++i) ov[i] = (__bf16)o[i];
    *reinterpret_cast<bf16x8*>((bf16*)out + (size_t)row * D_DIM + lane * 8) = ov;
  }
}

// ---------------------------------------------------------------------------
// Prep kernel: fused weight transposes (blocks 0..3327, R8-vectorized) +
// first LayerNorm h = LN(x) (blocks 3328..5375).
// ---------------------------------------------------------------------------
__global__ __launch_bounds__(256) void prep_kernel(
    const void* s0, const void* s1, const void* s2, const void* s3,
    const void* s4, const void* s5,
    bf16* d0, bf16* d1, bf16* d2, bf16* d3, bf16* d4, bf16* d5,
    const void* __restrict__ xin, const void* __restrict__ pre_g,
    const void* __restrict__ pre_b, bf16* __restrict__ hout,
    const unsigned* __restrict__ xdet)
{
  __shared__ float ftile[32][33];
  bool f32 = detect_f32(xdet);
  int bid = blockIdx.x;

  if (bid >= 3328) {
    // ---- LN path: h = LN(x) ----
    int wave = threadIdx.x >> 6;
    int lane = threadIdx.x & 63;
    int row  = (bid - 3328) * 4 + wave;

    float x[8];
    if (f32) {
      const float* rp = (const float*)xin + (size_t)row * D_DIM + lane * 8;
      float4 v0 = *reinterpret_cast<const float4*>(rp);
      float4 v1 = *reinterpret_cast<const float4*>(rp + 4);
      x[0]=v0.x; x[1]=v0.y; x[2]=v0.z; x[3]=v0.w;
      x[4]=v1.x; x[5]=v1.y; x[6]=v1.z; x[7]=v1.w;
    } else {
      bf16x8 v = *reinterpret_cast<const bf16x8*>(
          (const bf16*)xin + (size_t)row * D_DIM + lane * 8);
      #pragma unroll
      for (int i = 0; i < 8; ++i) x[i] = (float)v[i];
    }

    float s = 0.f, s2 = 0.f;
    #pragma unroll
    for (int i = 0; i < 8; ++i) { s += x[i]; s2 += x[i]*x[i]; }
    s  = wave_reduce_sum(s);
    s2 = wave_reduce_sum(s2);
    float mu   = s * (1.f / D_DIM);
    float var  = s2 * (1.f / D_DIM) - mu * mu;
    float rstd = rsqrtf(var + 1e-5f);

    bf16x8 ov;
    #pragma unroll
    for (int i = 0; i < 8; ++i) {
      int d = lane * 8 + i;
      ov[i] = (__bf16)((x[i] - mu) * rstd * rdP(pre_g, d, f32) + rdP(pre_b, d, f32));
    }
    *reinterpret_cast<bf16x8*>(hout + (size_t)row * D_DIM + lane * 8) = ov;
    return;
  }

  // ---- transpose path (vectorized) ----
  const void* src; bf16* dst; int R, C, lid, tiles_x;
  if      (bid < 256)  { src=s0; dst=d0; R=512;  C=512;  lid=bid;      tiles_x=16; }
  else if (bid < 768)  { src=s1; dst=d1; R=512;  C=1024; lid=bid-256;  tiles_x=32; }
  else if (bid < 1024) { src=s2; dst=d2; R=512;  C=512;  lid=bid-768;  tiles_x=16; }
  else if (bid < 1792) { src=s3; dst=d3; R=512;  C=1536; lid=bid-1024; tiles_x=48; }
  else if (bid < 2560) { src=s4; dst=d4; R=512;  C=1536; lid=bid-1792; tiles_x=48; }
  else                 { src=s5; dst=d5; R=1536; C=512;  lid=bid-2560; tiles_x=16; }

  int c0 = (lid % tiles_x) * 32;
  int r0 = (lid / tiles_x) * 32;

  // load: 256 threads x 4 elems = 32x32 tile, vector loads
  {
    int row = threadIdx.x >> 3;        // 0..31
    int c4  = (threadIdx.x & 7) * 4;   // 0,4..28
    if (f32) {
      float4 v = *reinterpret_cast<const float4*>(
          (const float*)src + (size_t)(r0 + row) * C + c0 + c4);
      ftile[row][c4]     = v.x;
      ftile[row][c4 + 1] = v.y;
      ftile[row][c4 + 2] = v.z;
      ftile[row][c4 + 3] = v.w;
    } else {
      bf16x4 v = *reinterpret_cast<const bf16x4*>(
          (const bf16*)src + (size_t)(r0 + row) * C + c0 + c4);
      #pragma unroll
      for (int i = 0; i < 4; ++i) ftile[row][c4 + i] = (float)v[i];
    }
  }
  __syncthreads();
  // store: transpose, bf16x4 packed 8B stores
  {
    int c  = threadIdx.x >> 3;         // 0..31
    int r4 = (threadIdx.x & 7) * 4;    // 0,4..28
    bf16x4 ov;
    #pragma unroll
    for (int i = 0; i < 4; ++i) ov[i] = (__bf16)ftile[r4 + i][c];
    *reinterpret_cast<bf16x4*>(dst + (size_t)(c0 + c) * R + r0 + r4) = ov;
  }
}

// ---------------------------------------------------------------------------
// 128 x BNT tile GEMM, BK=64 — 8-wave (512-thread) blocks, R5-exact pipeline
// (best measured config).
//   BNT=128: waves 2(M)x4(N), wave tile 64x32.  BNT=64: 4x2, tile 32x32.
// DBUF=false: m97 single-buffer (qkv). DBUF=true: 2-buffer + counted vmcnt.
// LDS linear for DMA; XOR swizzle on SOURCE + on ds_read (rule #21).
// Vectorized LDS-bounce epilogue (R4-validated).
// ---------------------------------------------------------------------------
template<int BNT, bool DBUF>
__global__ __launch_bounds__(512) void gemm_tile_kernel(
    const bf16* __restrict__ A, const bf16* __restrict__ Bt,
    bf16* Cout, const bf16* extra, int N, int K, int lda, int mode, int gx)
{
  constexpr int MI  = (BNT == 128) ? 4 : 2;   // M-frags per wave
  constexpr int NJ  = 2;                      // N-frags per wave
  constexpr int NB  = DBUF ? 2 : 1;
  constexpr int ASZ = 128 * BK;
  constexpr int BSZ = BNT * BK;
  constexpr int CPF = 68;    // f32 CT stride (BNT==64)
  constexpr int CPB = 136;   // bf16 CT stride (BNT==128)
  constexpr size_t STAGE = (size_t)NB * (ASZ + BSZ) * 2;
  constexpr size_t CTSZ  = (BNT == 64) ? (size_t)128 * CPF * 4 : (size_t)128 * CPB * 2;
  constexpr size_t SMEMSZ = STAGE > CTSZ ? STAGE : CTSZ;
  __shared__ alignas(16) char smem[SMEMSZ];
  bf16* Asb = (bf16*)smem;            // [NB][ASZ]
  bf16* Bsb = Asb + (size_t)NB * ASZ; // [NB][BSZ]

  int bx, by; swizzle_xy(gx, bx, by);
  int mbase = by * 128, nbase = bx * BNT;
  int tid  = threadIdx.x;
  int lane = tid & 63;
  int wid  = tid >> 6;
  int quad = lane >> 4, l16 = lane & 15;
  int wm, wn;
  if constexpr (BNT == 128) { wm = (wid >> 2) * 64; wn = (wid & 3) * 32; }
  else                      { wm = (wid >> 1) * 32; wn = (wid & 1) * 32; }

  // Staging map (512 threads): chunk covers LDS row tid>>3, col8 tid&7;
  // source col8 XOR'd by row&7 (both-sides swizzle). Issue 1 is row+64.
  int srow  = tid >> 3;
  int scolb = ((tid & 7) ^ (srow & 7)) * 8;
  const bf16* Ag = A  + (size_t)(mbase + srow) * lda + scolb;
  const bf16* Bg = Bt + (size_t)(nbase + srow) * K   + scolb;

  f32x4 acc[MI][NJ] = {};
  int nk = K / BK;

  auto stage = [&](int buf) {
    gload_lds16(Ag,                    &Asb[buf * ASZ + tid * 8]);
    gload_lds16(Ag + (size_t)64 * lda, &Asb[buf * ASZ + tid * 8 + 4096]);
    if constexpr (BNT == 128) {
      gload_lds16(Bg,                  &Bsb[buf * BSZ + tid * 8]);
      gload_lds16(Bg + (size_t)64 * K, &Bsb[buf * BSZ + tid * 8 + 4096]);
    } else {
      gload_lds16(Bg,                  &Bsb[buf * BSZ + tid * 8]);
    }
    Ag += BK; Bg += BK;
  };

  auto compute = [&](int cb) {
    #pragma unroll
    for (int ko = 0; ko < 2; ++ko) {
      bf16x8 a[MI], b[NJ];
      int c = ((ko * 4 + quad) ^ (l16 & 7)) * 8;
      #pragma unroll
      for (int i = 0; i < MI; ++i)
        a[i] = *reinterpret_cast<const bf16x8*>(&Asb[cb * ASZ + (wm + i * 16 + l16) * BK + c]);
      #pragma unroll
      for (int j = 0; j < NJ; ++j)
        b[j] = *reinterpret_cast<const bf16x8*>(&Bsb[cb * BSZ + (wn + j * 16 + l16) * BK + c]);
      #pragma unroll
      for (int i = 0; i < MI; ++i)
        #pragma unroll
        for (int j = 0; j < NJ; ++j)
          acc[i][j] = __builtin_amdgcn_mfma_f32_16x16x32_bf16(a[i], b[j], acc[i][j], 0, 0, 0);
    }
  };

  if constexpr (DBUF) {
    stage(0);
    for (int t = 0; t < nk; ++t) {
      int cur = t & 1;
      if (t + 1 < nk) {
        stage(cur ^ 1);
        if constexpr (BNT == 128) { WAIT_VM(4); } else { WAIT_VM(3); }
      } else {
        WAIT_VM(0);
      }
      SBAR();            // tile t visible; t+1 still in flight
      SCHED_FENCE();

      compute(cur);

      WAIT_LGKM0();      // this wave's ds_reads of buf[cur] complete
      SBAR();            // all waves done with buf[cur]
      SCHED_FENCE();
    }
  } else {
    for (int t = 0; t < nk; ++t) {
      __syncthreads();
      stage(0);
      __syncthreads();   // vmcnt(0) drain: DMA visible
      compute(0);
    }
    __syncthreads();     // all waves done reading LDS before CT reuse
  }

  // ---- vectorized epilogue via LDS bounce (512 threads) ----
  if constexpr (BNT == 64) {
    float* CT = (float*)smem;   // [128][CPF]
    #pragma unroll
    for (int i = 0; i < MI; ++i)
      #pragma unroll
      for (int j = 0; j < NJ; ++j)
        #pragma unroll
        for (int r = 0; r < 4; ++r)
          CT[(wm + i * 16 + quad * 4 + r) * CPF + wn + j * 16 + l16] = acc[i][j][r];
    __syncthreads();
    #pragma unroll
    for (int p = 0; p < 2; ++p) {
      int row = (tid >> 3) + p * 64;
      int c8  = tid & 7;
      const float* rp = &CT[row * CPF + c8 * 8];
      float4 v0 = *reinterpret_cast<const float4*>(rp);
      float4 v1 = *reinterpret_cast<const float4*>(rp + 4);
      float vv[8] = {v0.x, v0.y, v0.z, v0.w, v1.x, v1.y, v1.z, v1.w};
      size_t gidx = (size_t)(mbase + row) * N + nbase + c8 * 8;
      if (mode == 1) {
        bf16x8 e = *reinterpret_cast<const bf16x8*>(extra + gidx);
        #pragma unroll
        for (int k2 = 0; k2 < 8; ++k2) vv[k2] += (float)e[k2];
      }
      bf16x8 ov;
      #pragma unroll
      for (int k2 = 0; k2 < 8; ++k2) ov[k2] = (__bf16)vv[k2];
      *reinterpret_cast<bf16x8*>(Cout + gidx) = ov;
    }
  } else {
    bf16* CT = (bf16*)smem;     // [128][CPB], mode 0 only
    #pragma unroll
    for (int i = 0; i < MI; ++i)
      #pragma unroll
      for (int j = 0; j < NJ; ++j)
        #pragma unroll
        for (int r = 0; r < 4; ++r)
          CT[(wm + i * 16 + quad * 4 + r) * CPB + wn + j * 16 + l16] = f2b(acc[i][j][r]);
    __syncthreads();
    #pragma unroll
    for (int p = 0; p < 4; ++p) {
      int row = (tid >> 4) + p * 32;
      int c16 = tid & 15;
      bf16x8 ov = *reinterpret_cast<const bf16x8*>(&CT[row * CPB + c16 * 8]);
      *reinterpret_cast<bf16x8*>(Cout + (size_t)(mbase + row) * N + nbase + c16 * 8) = ov;
    }
  }
}

// ---------------------------------------------------------------------------
// Fused gate+val GEMM — R9: 128x128 tile, single-buffer m97 structure
// (qkv-identical shape). 48 KB LDS (A16+G16+V16), 8 waves 2Mx4N (wave tile
// 64x32), per K-step/wave: 32 MFMA vs 16 ds_read (2:1, was 1.33:1), B-panel
// re-fetch halved (12 n-tiles, was 24). Grid 768, gx=12.
// Vectorized epilogue: silu(g)*v in f32, bf16 bounce [128][136].
// ---------------------------------------------------------------------------
__global__ __launch_bounds__(512) void gateval_kernel(
    const bf16* __restrict__ A, const bf16* __restrict__ Btg,
    const bf16* __restrict__ Btv, bf16* __restrict__ Cout,
    int N, int K, int lda, int gx)
{
  constexpr int CP = 136;  // bf16 CT stride (272B rows, 16B-aligned)
  __shared__ alignas(16) char smem[3 * 16384];   // 48 KB (CT 34.8 KB fits)
  bf16* Asb = (bf16*)smem;          // [8192]
  bf16* Bgs = Asb + 8192;           // [8192]
  bf16* Bvs = Bgs + 8192;           // [8192]

  int bx, by; swizzle_xy(gx, bx, by);
  int mbase = by * 128, nbase = bx * 128;
  int tid  = threadIdx.x;
  int lane = tid & 63;
  int wid  = tid >> 6;
  int quad = lane >> 4, l16 = lane & 15;
  int wm = (wid >> 2) * 64, wn = (wid & 3) * 32;

  int srow  = tid >> 3;
  int scolb = ((tid & 7) ^ (srow & 7)) * 8;
  const bf16* Ag = A   + (size_t)(mbase + srow) * lda + scolb;
  const bf16* Gg = Btg + (size_t)(nbase + srow) * K   + scolb;
  const bf16* Vg = Btv + (size_t)(nbase + srow) * K   + scolb;

  f32x4 accg[4][2] = {};
  f32x4 accv[4][2] = {};
  int nk = K / BK;

  for (int t = 0; t < nk; ++t) {
    __syncthreads();
    gload_lds16(Ag,                    &Asb[tid * 8]);
    gload_lds16(Ag + (size_t)64 * lda, &Asb[tid * 8 + 4096]);
    gload_lds16(Gg,                    &Bgs[tid * 8]);
    gload_lds16(Gg + (size_t)64 * K,   &Bgs[tid * 8 + 4096]);
    gload_lds16(Vg,                    &Bvs[tid * 8]);
    gload_lds16(Vg + (size_t)64 * K,   &Bvs[tid * 8 + 4096]);
    Ag += BK; Gg += BK; Vg += BK;
    __syncthreads();   // vmcnt(0) drain: DMA visible

    #pragma unroll
    for (int ko = 0; ko < 2; ++ko) {
      bf16x8 a[4], bg[2], bv[2];
      int c = ((ko * 4 + quad) ^ (l16 & 7)) * 8;
      #pragma unroll
      for (int i = 0; i < 4; ++i)
        a[i]  = *reinterpret_cast<const bf16x8*>(&Asb[(wm + i * 16 + l16) * BK + c]);
      #pragma unroll
      for (int j = 0; j < 2; ++j) {
        bg[j] = *reinterpret_cast<const bf16x8*>(&Bgs[(wn + j * 16 + l16) * BK + c]);
        bv[j] = *reinterpret_cast<const bf16x8*>(&Bvs[(wn + j * 16 + l16) * BK + c]);
      }
      #pragma unroll
      for (int i = 0; i < 4; ++i)
        #pragma unroll
        for (int j = 0; j < 2; ++j) {
          accg[i][j] = __builtin_amdgcn_mfma_f32_16x16x32_bf16(a[i], bg[j], accg[i][j], 0, 0, 0);
          accv[i][j] = __builtin_amdgcn_mfma_f32_16x16x32_bf16(a[i], bv[j], accv[i][j], 0, 0, 0);
        }
    }
  }
  __syncthreads();     // all waves done reading LDS before CT reuse

  // ---- vectorized epilogue: silu(g)*v in f32, bf16 bounce, 16B stores ----
  bf16* CT = (bf16*)smem;   // [128][CP]
  #pragma unroll
  for (int i = 0; i < 4; ++i)
    #pragma unroll
    for (int j = 0; j < 2; ++j)
      #pragma unroll
      for (int r = 0; r < 4; ++r) {
        float g = accg[i][j][r];
        float v = accv[i][j][r];
        CT[(wm + i * 16 + quad * 4 + r) * CP + wn + j * 16 + l16] =
            f2b(g / (1.f + __expf(-g)) * v);
      }
  __syncthreads();
  #pragma unroll
  for (int p = 0; p < 4; ++p) {
    int row = (tid >> 4) + p * 32;
    int c16 = tid & 15;
    bf16x8 ov = *reinterpret_cast<const bf16x8*>(&CT[row * CP + c16 * 8]);
    *reinterpret_cast<bf16x8*>(Cout + (size_t)(mbase + row) * N + nbase + c16 * 8) = ov;
  }
}

// ---------------------------------------------------------------------------
// MFMA sliding-window sigmoid attention (R5 layout, __expf).
// ---------------------------------------------------------------------------
#define VT_BYTES 9216
#define PL_BYTES 2304
#define ATTN_SET (VT_BYTES + PL_BYTES)
__device__ __forceinline__ int vt_addr(int d, int t) { return d * 144 + t * 2; }

__global__ __launch_bounds__(256) void attn_mfma_kernel(bf16* qkv)
{
  __shared__ alignas(16) char lds_raw[4 * ATTN_SET];
  int lane = threadIdx.x & 63;
  int widx = threadIdx.x >> 6;
  int u    = blockIdx.x * 4 + widx;
  int tile = u >> 3, head = u & 7;
  int rowbase = tile * 16;
  int t0   = rowbase & (T_LEN - 1);
  int l16  = lane & 15, quad = lane >> 4;

  char* wbase = lds_raw + widx * ATTN_SET;
  char* Vl = wbase;
  bf16* Pl = (bf16*)(wbase + VT_BYTES);

  #pragma unroll
  for (int it = 0; it < 6; ++it) {
    int chunk = it * 64 + lane;
    int t  = chunk >> 3;
    int dc = chunk & 7;
    int row = rowbase - 32 + t;
    if (row < 0) row = 0;             // garbage ok: masked by tau=0
    bf16x8 v = *reinterpret_cast<const bf16x8*>(
        qkv + (size_t)row * QKV_LD + 512 + head * 128 + 64 + dc * 8);
    #pragma unroll
    for (int jj = 0; jj < 8; ++jj)
      *(bf16*)(Vl + vt_addr(dc * 8 + jj, t)) = (bf16)(__bf16)v[jj];
  }
  bf16x8 z = {};
  *reinterpret_cast<bf16x8*>(Vl + vt_addr(lane, 48)) = z;
  *reinterpret_cast<bf16x8*>(Vl + vt_addr(lane, 56)) = z;

  bf16x8 aq0, aq1;
  {
    const bf16* qrow = qkv + (size_t)(rowbase + l16) * QKV_LD + head * HD_DIM + quad * 8;
    aq0 = *reinterpret_cast<const bf16x8*>(qrow);
    aq1 = *reinterpret_cast<const bf16x8*>(qrow + 32);
  }

  f32x4 sacc[3] = {};
  #pragma unroll
  for (int jt = 0; jt < 3; ++jt) {
    int tok = rowbase - 32 + jt * 16 + l16;
    if (tok < 0) tok = 0;             // garbage ok: masked
    const bf16* krow = qkv + (size_t)tok * QKV_LD + 512 + head * 128 + quad * 8;
    bf16x8 b0 = *reinterpret_cast<const bf16x8*>(krow);
    bf16x8 b1 = *reinterpret_cast<const bf16x8*>(krow + 32);
    sacc[jt] = __builtin_amdgcn_mfma_f32_16x16x32_bf16(aq0, b0, sacc[jt], 0, 0, 0);
    sacc[jt] = __builtin_amdgcn_mfma_f32_16x16x32_bf16(aq1, b1, sacc[jt], 0, 0, 0);
  }

  #pragma unroll
  for (int jt = 0; jt < 3; ++jt) {
    int j = jt * 16 + l16;
    #pragma unroll
    for (int r = 0; r < 4; ++r) {
      int i = quad * 4 + r;
      bool valid = (j >= i) && (j <= i + 31) && (t0 - 32 + j >= 0);
      float tau = valid ? 1.f / (1.f + __expf(-sacc[jt][r] * 0.125f)) : 0.f;
      Pl[i * 72 + j] = f2b(tau);
    }
  }
  #pragma unroll
  for (int r = 0; r < 4; ++r) Pl[(quad * 4 + r) * 72 + 48 + l16] = f2b(0.f);

  __syncthreads();   // uniform; orders LDS writes->reads across the block

  bf16x8 ap0 = *reinterpret_cast<const bf16x8*>((char*)Pl + l16 * 144 + quad * 16);
  bf16x8 ap1 = *reinterpret_cast<const bf16x8*>((char*)Pl + l16 * 144 + 64 + quad * 16);

  f32x4 macc[4] = {};
  #pragma unroll
  for (int nt = 0; nt < 4; ++nt) {
    int d = nt * 16 + l16;
    bf16x8 bv0 = *reinterpret_cast<const bf16x8*>(Vl + vt_addr(d, quad * 8));
    bf16x8 bv1 = *reinterpret_cast<const bf16x8*>(Vl + vt_addr(d, 32 + quad * 8));
    macc[nt] = __builtin_amdgcn_mfma_f32_16x16x32_bf16(ap0, bv0, macc[nt], 0, 0, 0);
    macc[nt] = __builtin_amdgcn_mfma_f32_16x16x32_bf16(ap1, bv1, macc[nt], 0, 0, 0);
  }

  // ---- vectorized output: bounce 16x64 tile through Pl region ----
  #pragma unroll
  for (int nt = 0; nt < 4; ++nt)
    #pragma unroll
    for (int r = 0; r < 4; ++r)
      Pl[(quad * 4 + r) * 72 + nt * 16 + l16] = f2b(macc[nt][r]);

  #pragma unroll
  for (int p = 0; p < 2; ++p) {
    int row = (lane >> 3) + p * 8;
    int c8  = lane & 7;
    bf16x8 ov = *reinterpret_cast<const bf16x8*>(&Pl[row * 72 + c8 * 8]);
    *reinterpret_cast<bf16x8*>(
        qkv + (size_t)(rowbase + row) * QKV_LD + head * HD_DIM + c8 * 8) = ov;
  }
}

// ---------------------------------------------------------------------------
extern "C" void kernel_launch(void* const* d_in, const int* in_sizes, int n_in,
                              void* d_out, int out_size, void* d_ws, size_t ws_size,
                              hipStream_t stream)
{
  const void* x      = d_in[0];
  const void* pre_g  = d_in[1];
  const void* pre_b  = d_in[2];
  const void* wq     = d_in[3];
  const void* wkv    = d_in[4];
  const void* wo     = d_in[5];
  const void* attn_g = d_in[6];
  const void* attn_b = d_in[7];
  const void* freqs  = d_in[8];
  const void* phases = d_in[9];
  const void* amp    = d_in[10];
  const void* w_gate = d_in[11];
  const void* w_val  = d_in[12];
  const void* w_proj = d_in[13];
  const void* ffn_g  = d_in[14];
  const void* ffn_b  = d_in[15];
  const unsigned* xdet = (const unsigned*)x;

  char* ws = (char*)d_ws;
  bf16* Btqkv = (bf16*)(ws + 512);       // 1536 x 512
  bf16* Bto   = (bf16*)(ws + 1573376);   //  512 x 512
  bf16* Btg   = (bf16*)(ws + 2097664);   // 1536 x 512
  bf16* Btv   = (bf16*)(ws + 3670528);   // 1536 x 512
  bf16* Btp   = (bf16*)(ws + 5243392);   //  512 x 1536
  bf16* h     = (bf16*)(ws + 6816256);   // 8192 x 512   (h -> s1 -> y -> u)
  bf16* qkvb  = (bf16*)(ws + 15204864);  // 8192 x 1536  (q|kv; msg in-place; then act)
  bf16* gb    = qkvb;

  // transposes + h = LN(x), fused
  prep_kernel<<<5376, 256, 0, stream>>>(
      wq, wkv, wo, w_gate, w_val, w_proj,
      Btqkv, Btqkv + 512 * 512, Bto, Btg, Btv, Btp,
      x, pre_g, pre_b, h, xdet);

  // qkv = h @ [wq|wkv]  (N=1536): 128x128 single-buffer, 8 waves, 768 blocks
  gemm_tile_kernel<128, false><<<768, 512, 0, stream>>>(h, Btqkv, qkvb, nullptr,
                                                        1536, 512, 512, 0, 12);

  // msg = window-attention (in-place over q slot)
  attn_mfma_kernel<<<1024, 256, 0, stream>>>(qkvb);

  // s1 = h + msg @ wo  (N=512): 128x64 2-buffer pipeline, 512 blocks
  gemm_tile_kernel<64, true><<<512, 512, 0, stream>>>(qkvb, Bto, h, h,
                                                      512, 512, QKV_LD, 1, 8);

  // y = LN(s1) * (1 + amp*sin(t*freqs+phases))
  ln_kernel<<<2048, 256, 0, stream>>>(h, attn_g, attn_b, h, 1,
                                      freqs, phases, amp, xdet, 0, 0);

  // act = silu(y @ w_gate) * (y @ w_val): 128x128 single-buffer, 768 blocks
  gateval_kernel<<<768, 512, 0, stream>>>(h, Btg, Btv, gb,
                                          1536, 512, 512, 12);

  // u = y + act @ w_proj  (N=512, K=1536): 128x64 2-buffer, 512 blocks
  gemm_tile_kernel<64, true><<<512, 512, 0, stream>>>(gb, Btp, h, h,
                                                      512, 1536, QKV_LD, 1, 8);

  // out = LN(u)
  ln_kernel<<<2048, 256, 0, stream>>>(h, ffn_g, ffn_b, d_out, 0,
                                      nullptr, nullptr, nullptr, xdet, 0, 1);
}

// Round 10
// 258.696 us; speedup vs baseline: 1.0164x; 1.0164x over previous
//
#include <hip/hip_runtime.h>
#include <hip/hip_bf16.h>
#include <math.h>

// Problem constants
#define T_LEN   4096
#define D_DIM   512
#define H_NUM   8
#define HD_DIM  64
#define W_WIN   32
#define HID_DIM 1536
#define M_ROWS  8192   // B*T
#define QKV_LD  1536   // fused q|kv row stride
#define BK 64

typedef __hip_bfloat16 bf16;
typedef __bf16  bf16x8 __attribute__((ext_vector_type(8)));
typedef __bf16  bf16x4 __attribute__((ext_vector_type(4)));
typedef float   f32x4  __attribute__((ext_vector_type(4)));

#define G_AS __attribute__((address_space(1)))
#define L_AS __attribute__((address_space(3)))

#define SBAR()        __builtin_amdgcn_s_barrier()
#define SCHED_FENCE() __builtin_amdgcn_sched_barrier(0)
#define WAIT_VM(N)    asm volatile("s_waitcnt vmcnt(" #N ")" ::: "memory")
#define WAIT_LGKM0()  asm volatile("s_waitcnt lgkmcnt(0)" ::: "memory")

__device__ __forceinline__ float b2f(bf16 x) { return __bfloat162float(x); }
__device__ __forceinline__ bf16  f2b(float x){ return __float2bfloat16(x); }

// 16B async global->LDS DMA (gfx950). Dest must be linear: base + lane*16.
__device__ __forceinline__ void gload_lds16(const bf16* g, bf16* l) {
  __builtin_amdgcn_global_load_lds((const G_AS unsigned int*)g,
                                   (L_AS unsigned int*)l, 16, 0, 0);
}

__device__ __forceinline__ float rdP(const void* p, int i, bool f32) {
  return f32 ? ((const float*)p)[i] : b2f(((const bf16*)p)[i]);
}

__device__ __forceinline__ float wave_reduce_sum(float v) {
  #pragma unroll
  for (int off = 32; off; off >>= 1) v += __shfl_xor(v, off, 64);
  return v;
}

// Wave-parallel dtype detection over a fixed 256 dwords of x (deterministic).
__device__ __forceinline__ bool detect_f32(const unsigned* __restrict__ x) {
  int lane = threadIdx.x & 63;
  int votes = 0;
  #pragma unroll
  for (int i = 0; i < 4; ++i) {
    unsigned e = (x[lane * 4 + i] >> 7) & 0xffu;
    votes += (e >= 90u && e <= 140u) ? 1 : 0;
  }
  float v = wave_reduce_sum((float)votes);
  return v < 200.f;
}

// XCD-aware 1-D block swizzle (R8-validated): lid%8 = XCD; same-by tiles
// land on one XCD so the A row-panel is fetched into exactly one L2.
// All grids used are multiples of 8 -> bijective.
__device__ __forceinline__ void swizzle_xy(int gx, int& bx, int& by) {
  int lid = blockIdx.x;
  int sub = lid & 7;
  int grp = lid >> 3;
  bx = grp % gx;
  by = (grp / gx) * 8 + sub;
}

// ---------------------------------------------------------------------------
// LayerNorm (R2-validated numerics; self-detecting dtype).
// ---------------------------------------------------------------------------
__global__ __launch_bounds__(256) void ln_kernel(
    const void* __restrict__ in, const void* __restrict__ g, const void* __restrict__ bb,
    void* __restrict__ out, int mode,
    const void* __restrict__ freqs, const void* __restrict__ phases,
    const void* __restrict__ amp,
    const unsigned* __restrict__ xdet, int in_follows, int out_follows)
{
  bool f32  = detect_f32(xdet);
  bool inF  = f32 && (in_follows != 0);
  bool outF = f32 && (out_follows != 0);

  int wave = threadIdx.x >> 6;
  int lane = threadIdx.x & 63;
  int row  = blockIdx.x * 4 + wave;

  float x[8];
  if (inF) {
    const float* rp = (const float*)in + (size_t)row * D_DIM + lane * 8;
    float4 v0 = *reinterpret_cast<const float4*>(rp);
    float4 v1 = *reinterpret_cast<const float4*>(rp + 4);
    x[0]=v0.x; x[1]=v0.y; x[2]=v0.z; x[3]=v0.w;
    x[4]=v1.x; x[5]=v1.y; x[6]=v1.z; x[7]=v1.w;
  } else {
    bf16x8 v = *reinterpret_cast<const bf16x8*>(
        (const bf16*)in + (size_t)row * D_DIM + lane * 8);
    #pragma unroll
    for (int i = 0; i < 8; ++i) x[i] = (float)v[i];
  }

  float s = 0.f, s2 = 0.f;
  #pragma unroll
  for (int i = 0; i < 8; ++i) { s += x[i]; s2 += x[i]*x[i]; }
  s  = wave_reduce_sum(s);
  s2 = wave_reduce_sum(s2);
  float mu   = s * (1.f / D_DIM);
  float var  = s2 * (1.f / D_DIM) - mu * mu;
  float rstd = rsqrtf(var + 1e-5f);

  int t = row & (T_LEN - 1);
  float ampf = (mode == 1) ? rdP(amp, 0, f32) : 0.f;

  float o[8];
  #pragma unroll
  for (int i = 0; i < 8; ++i) {
    int d = lane * 8 + i;
    float val = (x[i] - mu) * rstd * rdP(g, d, f32) + rdP(bb, d, f32);
    if (mode == 1) {
      float m = __sinf(fmaf((float)t, rdP(freqs, d, f32), rdP(phases, d, f32)));
      val *= (1.f + ampf * m);
    }
    o[i] = val;
  }

  if (outF) {
    float* op = (float*)out + (size_t)row * D_DIM + lane * 8;
    *reinterpret_cast<float4*>(op)     = make_float4(o[0], o[1], o[2], o[3]);
    *reinterpret_cast<float4*>(op + 4) = make_float4(o[4], o[5], o[6], o[7]);
  } else {
    bf16x8 ov;
    #pragma unroll
    for (int i = 0; i < 8; ++i) ov[i] = (__bf16)o[i];
    *reinterpret_cast<bf16x8*>((bf16*)out + (size_t)row * D_DIM + lane * 8) = ov;
  }
}

// ---------------------------------------------------------------------------
// Prep kernel: fused weight transposes (blocks 0..3327, R8-vectorized) +
// first LayerNorm h = LN(x) (blocks 3328..5375).
// ---------------------------------------------------------------------------
__global__ __launch_bounds__(256) void prep_kernel(
    const void* s0, const void* s1, const void* s2, const void* s3,
    const void* s4, const void* s5,
    bf16* d0, bf16* d1, bf16* d2, bf16* d3, bf16* d4, bf16* d5,
    const void* __restrict__ xin, const void* __restrict__ pre_g,
    const void* __restrict__ pre_b, bf16* __restrict__ hout,
    const unsigned* __restrict__ xdet)
{
  __shared__ float ftile[32][33];
  bool f32 = detect_f32(xdet);
  int bid = blockIdx.x;

  if (bid >= 3328) {
    // ---- LN path: h = LN(x) ----
    int wave = threadIdx.x >> 6;
    int lane = threadIdx.x & 63;
    int row  = (bid - 3328) * 4 + wave;

    float x[8];
    if (f32) {
      const float* rp = (const float*)xin + (size_t)row * D_DIM + lane * 8;
      float4 v0 = *reinterpret_cast<const float4*>(rp);
      float4 v1 = *reinterpret_cast<const float4*>(rp + 4);
      x[0]=v0.x; x[1]=v0.y; x[2]=v0.z; x[3]=v0.w;
      x[4]=v1.x; x[5]=v1.y; x[6]=v1.z; x[7]=v1.w;
    } else {
      bf16x8 v = *reinterpret_cast<const bf16x8*>(
          (const bf16*)xin + (size_t)row * D_DIM + lane * 8);
      #pragma unroll
      for (int i = 0; i < 8; ++i) x[i] = (float)v[i];
    }

    float s = 0.f, s2 = 0.f;
    #pragma unroll
    for (int i = 0; i < 8; ++i) { s += x[i]; s2 += x[i]*x[i]; }
    s  = wave_reduce_sum(s);
    s2 = wave_reduce_sum(s2);
    float mu   = s * (1.f / D_DIM);
    float var  = s2 * (1.f / D_DIM) - mu * mu;
    float rstd = rsqrtf(var + 1e-5f);

    bf16x8 ov;
    #pragma unroll
    for (int i = 0; i < 8; ++i) {
      int d = lane * 8 + i;
      ov[i] = (__bf16)((x[i] - mu) * rstd * rdP(pre_g, d, f32) + rdP(pre_b, d, f32));
    }
    *reinterpret_cast<bf16x8*>(hout + (size_t)row * D_DIM + lane * 8) = ov;
    return;
  }

  // ---- transpose path (vectorized) ----
  const void* src; bf16* dst; int R, C, lid, tiles_x;
  if      (bid < 256)  { src=s0; dst=d0; R=512;  C=512;  lid=bid;      tiles_x=16; }
  else if (bid < 768)  { src=s1; dst=d1; R=512;  C=1024; lid=bid-256;  tiles_x=32; }
  else if (bid < 1024) { src=s2; dst=d2; R=512;  C=512;  lid=bid-768;  tiles_x=16; }
  else if (bid < 1792) { src=s3; dst=d3; R=512;  C=1536; lid=bid-1024; tiles_x=48; }
  else if (bid < 2560) { src=s4; dst=d4; R=512;  C=1536; lid=bid-1792; tiles_x=48; }
  else                 { src=s5; dst=d5; R=1536; C=512;  lid=bid-2560; tiles_x=16; }

  int c0 = (lid % tiles_x) * 32;
  int r0 = (lid / tiles_x) * 32;

  // load: 256 threads x 4 elems = 32x32 tile, vector loads
  {
    int row = threadIdx.x >> 3;        // 0..31
    int c4  = (threadIdx.x & 7) * 4;   // 0,4..28
    if (f32) {
      float4 v = *reinterpret_cast<const float4*>(
          (const float*)src + (size_t)(r0 + row) * C + c0 + c4);
      ftile[row][c4]     = v.x;
      ftile[row][c4 + 1] = v.y;
      ftile[row][c4 + 2] = v.z;
      ftile[row][c4 + 3] = v.w;
    } else {
      bf16x4 v = *reinterpret_cast<const bf16x4*>(
          (const bf16*)src + (size_t)(r0 + row) * C + c0 + c4);
      #pragma unroll
      for (int i = 0; i < 4; ++i) ftile[row][c4 + i] = (float)v[i];
    }
  }
  __syncthreads();
  // store: transpose, bf16x4 packed 8B stores
  {
    int c  = threadIdx.x >> 3;         // 0..31
    int r4 = (threadIdx.x & 7) * 4;    // 0,4..28
    bf16x4 ov;
    #pragma unroll
    for (int i = 0; i < 4; ++i) ov[i] = (__bf16)ftile[r4 + i][c];
    *reinterpret_cast<bf16x4*>(dst + (size_t)(c0 + c) * R + r0 + r4) = ov;
  }
}

// ---------------------------------------------------------------------------
// 128 x BNT tile GEMM, BK=64 — 8-wave (512-thread) blocks, R5-exact pipeline
// (best measured config).
//   BNT=128: waves 2(M)x4(N), wave tile 64x32.  BNT=64: 4x2, tile 32x32.
// DBUF=false: m97 single-buffer (qkv). DBUF=true: 2-buffer + counted vmcnt.
// LDS linear for DMA; XOR swizzle on SOURCE + on ds_read (rule #21).
// Vectorized LDS-bounce epilogue (R4-validated).
// R10: mode-1 `extra` loads hoisted BEFORE the CT bounce (issue-early /
// use-late — overlaps their HBM/L2 latency with the bounce write+sync).
// ---------------------------------------------------------------------------
template<int BNT, bool DBUF>
__global__ __launch_bounds__(512) void gemm_tile_kernel(
    const bf16* __restrict__ A, const bf16* __restrict__ Bt,
    bf16* Cout, const bf16* extra, int N, int K, int lda, int mode, int gx)
{
  constexpr int MI  = (BNT == 128) ? 4 : 2;   // M-frags per wave
  constexpr int NJ  = 2;                      // N-frags per wave
  constexpr int NB  = DBUF ? 2 : 1;
  constexpr int ASZ = 128 * BK;
  constexpr int BSZ = BNT * BK;
  constexpr int CPF = 68;    // f32 CT stride (BNT==64)
  constexpr int CPB = 136;   // bf16 CT stride (BNT==128)
  constexpr size_t STAGE = (size_t)NB * (ASZ + BSZ) * 2;
  constexpr size_t CTSZ  = (BNT == 64) ? (size_t)128 * CPF * 4 : (size_t)128 * CPB * 2;
  constexpr size_t SMEMSZ = STAGE > CTSZ ? STAGE : CTSZ;
  __shared__ alignas(16) char smem[SMEMSZ];
  bf16* Asb = (bf16*)smem;            // [NB][ASZ]
  bf16* Bsb = Asb + (size_t)NB * ASZ; // [NB][BSZ]

  int bx, by; swizzle_xy(gx, bx, by);
  int mbase = by * 128, nbase = bx * BNT;
  int tid  = threadIdx.x;
  int lane = tid & 63;
  int wid  = tid >> 6;
  int quad = lane >> 4, l16 = lane & 15;
  int wm, wn;
  if constexpr (BNT == 128) { wm = (wid >> 2) * 64; wn = (wid & 3) * 32; }
  else                      { wm = (wid >> 1) * 32; wn = (wid & 1) * 32; }

  // Staging map (512 threads): chunk covers LDS row tid>>3, col8 tid&7;
  // source col8 XOR'd by row&7 (both-sides swizzle). Issue 1 is row+64.
  int srow  = tid >> 3;
  int scolb = ((tid & 7) ^ (srow & 7)) * 8;
  const bf16* Ag = A  + (size_t)(mbase + srow) * lda + scolb;
  const bf16* Bg = Bt + (size_t)(nbase + srow) * K   + scolb;

  f32x4 acc[MI][NJ] = {};
  int nk = K / BK;

  auto stage = [&](int buf) {
    gload_lds16(Ag,                    &Asb[buf * ASZ + tid * 8]);
    gload_lds16(Ag + (size_t)64 * lda, &Asb[buf * ASZ + tid * 8 + 4096]);
    if constexpr (BNT == 128) {
      gload_lds16(Bg,                  &Bsb[buf * BSZ + tid * 8]);
      gload_lds16(Bg + (size_t)64 * K, &Bsb[buf * BSZ + tid * 8 + 4096]);
    } else {
      gload_lds16(Bg,                  &Bsb[buf * BSZ + tid * 8]);
    }
    Ag += BK; Bg += BK;
  };

  auto compute = [&](int cb) {
    #pragma unroll
    for (int ko = 0; ko < 2; ++ko) {
      bf16x8 a[MI], b[NJ];
      int c = ((ko * 4 + quad) ^ (l16 & 7)) * 8;
      #pragma unroll
      for (int i = 0; i < MI; ++i)
        a[i] = *reinterpret_cast<const bf16x8*>(&Asb[cb * ASZ + (wm + i * 16 + l16) * BK + c]);
      #pragma unroll
      for (int j = 0; j < NJ; ++j)
        b[j] = *reinterpret_cast<const bf16x8*>(&Bsb[cb * BSZ + (wn + j * 16 + l16) * BK + c]);
      #pragma unroll
      for (int i = 0; i < MI; ++i)
        #pragma unroll
        for (int j = 0; j < NJ; ++j)
          acc[i][j] = __builtin_amdgcn_mfma_f32_16x16x32_bf16(a[i], b[j], acc[i][j], 0, 0, 0);
    }
  };

  if constexpr (DBUF) {
    stage(0);
    for (int t = 0; t < nk; ++t) {
      int cur = t & 1;
      if (t + 1 < nk) {
        stage(cur ^ 1);
        if constexpr (BNT == 128) { WAIT_VM(4); } else { WAIT_VM(3); }
      } else {
        WAIT_VM(0);
      }
      SBAR();            // tile t visible; t+1 still in flight
      SCHED_FENCE();

      compute(cur);

      WAIT_LGKM0();      // this wave's ds_reads of buf[cur] complete
      SBAR();            // all waves done with buf[cur]
      SCHED_FENCE();
    }
  } else {
    for (int t = 0; t < nk; ++t) {
      __syncthreads();
      stage(0);
      __syncthreads();   // vmcnt(0) drain: DMA visible
      compute(0);
    }
    __syncthreads();     // all waves done reading LDS before CT reuse
  }

  // ---- vectorized epilogue via LDS bounce (512 threads) ----
  if constexpr (BNT == 64) {
    // R10: issue residual loads FIRST — overlap latency with CT bounce.
    bf16x8 e[2];
    if (mode == 1) {
      #pragma unroll
      for (int p = 0; p < 2; ++p) {
        int row = (tid >> 3) + p * 64;
        int c8  = tid & 7;
        e[p] = *reinterpret_cast<const bf16x8*>(
            extra + (size_t)(mbase + row) * N + nbase + c8 * 8);
      }
    }
    float* CT = (float*)smem;   // [128][CPF]
    #pragma unroll
    for (int i = 0; i < MI; ++i)
      #pragma unroll
      for (int j = 0; j < NJ; ++j)
        #pragma unroll
        for (int r = 0; r < 4; ++r)
          CT[(wm + i * 16 + quad * 4 + r) * CPF + wn + j * 16 + l16] = acc[i][j][r];
    __syncthreads();
    #pragma unroll
    for (int p = 0; p < 2; ++p) {
      int row = (tid >> 3) + p * 64;
      int c8  = tid & 7;
      const float* rp = &CT[row * CPF + c8 * 8];
      float4 v0 = *reinterpret_cast<const float4*>(rp);
      float4 v1 = *reinterpret_cast<const float4*>(rp + 4);
      float vv[8] = {v0.x, v0.y, v0.z, v0.w, v1.x, v1.y, v1.z, v1.w};
      size_t gidx = (size_t)(mbase + row) * N + nbase + c8 * 8;
      if (mode == 1) {
        #pragma unroll
        for (int k2 = 0; k2 < 8; ++k2) vv[k2] += (float)e[p][k2];
      }
      bf16x8 ov;
      #pragma unroll
      for (int k2 = 0; k2 < 8; ++k2) ov[k2] = (__bf16)vv[k2];
      *reinterpret_cast<bf16x8*>(Cout + gidx) = ov;
    }
  } else {
    bf16* CT = (bf16*)smem;     // [128][CPB], mode 0 only
    #pragma unroll
    for (int i = 0; i < MI; ++i)
      #pragma unroll
      for (int j = 0; j < NJ; ++j)
        #pragma unroll
        for (int r = 0; r < 4; ++r)
          CT[(wm + i * 16 + quad * 4 + r) * CPB + wn + j * 16 + l16] = f2b(acc[i][j][r]);
    __syncthreads();
    #pragma unroll
    for (int p = 0; p < 4; ++p) {
      int row = (tid >> 4) + p * 32;
      int c16 = tid & 15;
      bf16x8 ov = *reinterpret_cast<const bf16x8*>(&CT[row * CPB + c16 * 8]);
      *reinterpret_cast<bf16x8*>(Cout + (size_t)(mbase + row) * N + nbase + c16 * 8) = ov;
    }
  }
}

// ---------------------------------------------------------------------------
// Fused gate+val GEMM, 128x64 tile — 8-wave 2-buffer counted-vmcnt pipeline
// (R5/R8-validated best; R9's 128x128 single-buffer regressed — reverted),
// vectorized epilogue, __expf.
// ---------------------------------------------------------------------------
__global__ __launch_bounds__(512) void gateval_kernel(
    const bf16* __restrict__ A, const bf16* __restrict__ Btg,
    const bf16* __restrict__ Btv, bf16* __restrict__ Cout,
    int N, int K, int lda, int gx)
{
  constexpr int CP = 72;   // bf16 CT stride
  __shared__ alignas(16) char smem[2 * (16384 + 8192 + 8192)];  // 64 KB
  bf16* Asb = (bf16*)smem;                    // [2][8192]
  bf16* Bgs = Asb + 2 * 8192;                 // [2][4096]
  bf16* Bvs = Bgs + 2 * 4096;                 // [2][4096]

  int bx, by; swizzle_xy(gx, bx, by);
  int mbase = by * 128, nbase = bx * 64;
  int tid  = threadIdx.x;
  int lane = tid & 63;
  int wid  = tid >> 6;
  int quad = lane >> 4, l16 = lane & 15;
  int wm = (wid >> 1) * 32, wn = (wid & 1) * 32;

  int srow  = tid >> 3;
  int scolb = ((tid & 7) ^ (srow & 7)) * 8;
  const bf16* Ag = A   + (size_t)(mbase + srow) * lda + scolb;
  const bf16* Gg = Btg + (size_t)(nbase + srow) * K   + scolb;
  const bf16* Vg = Btv + (size_t)(nbase + srow) * K   + scolb;

  f32x4 accg[2][2] = {};
  f32x4 accv[2][2] = {};
  int nk = K / BK;

  auto stage = [&](int buf) {
    gload_lds16(Ag,                    &Asb[buf * 8192 + tid * 8]);
    gload_lds16(Ag + (size_t)64 * lda, &Asb[buf * 8192 + tid * 8 + 4096]);
    gload_lds16(Gg,                    &Bgs[buf * 4096 + tid * 8]);
    gload_lds16(Vg,                    &Bvs[buf * 4096 + tid * 8]);
    Ag += BK; Gg += BK; Vg += BK;
  };

  stage(0);
  for (int t = 0; t < nk; ++t) {
    int cur = t & 1;
    if (t + 1 < nk) {
      stage(cur ^ 1);
      WAIT_VM(4);
    } else {
      WAIT_VM(0);
    }
    SBAR();
    SCHED_FENCE();

    #pragma unroll
    for (int ko = 0; ko < 2; ++ko) {
      bf16x8 a[2], bg[2], bv[2];
      int c = ((ko * 4 + quad) ^ (l16 & 7)) * 8;
      #pragma unroll
      for (int i = 0; i < 2; ++i)
        a[i]  = *reinterpret_cast<const bf16x8*>(&Asb[cur * 8192 + (wm + i * 16 + l16) * BK + c]);
      #pragma unroll
      for (int j = 0; j < 2; ++j) {
        bg[j] = *reinterpret_cast<const bf16x8*>(&Bgs[cur * 4096 + (wn + j * 16 + l16) * BK + c]);
        bv[j] = *reinterpret_cast<const bf16x8*>(&Bvs[cur * 4096 + (wn + j * 16 + l16) * BK + c]);
      }
      #pragma unroll
      for (int i = 0; i < 2; ++i)
        #pragma unroll
        for (int j = 0; j < 2; ++j) {
          accg[i][j] = __builtin_amdgcn_mfma_f32_16x16x32_bf16(a[i], bg[j], accg[i][j], 0, 0, 0);
          accv[i][j] = __builtin_amdgcn_mfma_f32_16x16x32_bf16(a[i], bv[j], accv[i][j], 0, 0, 0);
        }
    }

    WAIT_LGKM0();
    SBAR();
    SCHED_FENCE();
  }

  // ---- vectorized epilogue: silu(g)*v in f32, bf16 bounce, 16B stores ----
  bf16* CT = (bf16*)smem;   // [128][CP]
  #pragma unroll
  for (int i = 0; i < 2; ++i)
    #pragma unroll
    for (int j = 0; j < 2; ++j)
      #pragma unroll
      for (int r = 0; r < 4; ++r) {
        float g = accg[i][j][r];
        float v = accv[i][j][r];
        CT[(wm + i * 16 + quad * 4 + r) * CP + wn + j * 16 + l16] =
            f2b(g / (1.f + __expf(-g)) * v);
      }
  __syncthreads();
  #pragma unroll
  for (int p = 0; p < 2; ++p) {
    int row = (tid >> 3) + p * 64;
    int c8  = tid & 7;
    bf16x8 ov = *reinterpret_cast<const bf16x8*>(&CT[row * CP + c8 * 8]);
    *reinterpret_cast<bf16x8*>(Cout + (size_t)(mbase + row) * N + nbase + c8 * 8) = ov;
  }
}

// ---------------------------------------------------------------------------
// MFMA sliding-window sigmoid attention (R5 layout, __expf).
// ---------------------------------------------------------------------------
#define VT_BYTES 9216
#define PL_BYTES 2304
#define ATTN_SET (VT_BYTES + PL_BYTES)
__device__ __forceinline__ int vt_addr(int d, int t) { return d * 144 + t * 2; }

__global__ __launch_bounds__(256) void attn_mfma_kernel(bf16* qkv)
{
  __shared__ alignas(16) char lds_raw[4 * ATTN_SET];
  int lane = threadIdx.x & 63;
  int widx = threadIdx.x >> 6;
  int u    = blockIdx.x * 4 + widx;
  int tile = u >> 3, head = u & 7;
  int rowbase = tile * 16;
  int t0   = rowbase & (T_LEN - 1);
  int l16  = lane & 15, quad = lane >> 4;

  char* wbase = lds_raw + widx * ATTN_SET;
  char* Vl = wbase;
  bf16* Pl = (bf16*)(wbase + VT_BYTES);

  #pragma unroll
  for (int it = 0; it < 6; ++it) {
    int chunk = it * 64 + lane;
    int t  = chunk >> 3;
    int dc = chunk & 7;
    int row = rowbase - 32 + t;
    if (row < 0) row = 0;             // garbage ok: masked by tau=0
    bf16x8 v = *reinterpret_cast<const bf16x8*>(
        qkv + (size_t)row * QKV_LD + 512 + head * 128 + 64 + dc * 8);
    #pragma unroll
    for (int jj = 0; jj < 8; ++jj)
      *(bf16*)(Vl + vt_addr(dc * 8 + jj, t)) = (bf16)(__bf16)v[jj];
  }
  bf16x8 z = {};
  *reinterpret_cast<bf16x8*>(Vl + vt_addr(lane, 48)) = z;
  *reinterpret_cast<bf16x8*>(Vl + vt_addr(lane, 56)) = z;

  bf16x8 aq0, aq1;
  {
    const bf16* qrow = qkv + (size_t)(rowbase + l16) * QKV_LD + head * HD_DIM + quad * 8;
    aq0 = *reinterpret_cast<const bf16x8*>(qrow);
    aq1 = *reinterpret_cast<const bf16x8*>(qrow + 32);
  }

  f32x4 sacc[3] = {};
  #pragma unroll
  for (int jt = 0; jt < 3; ++jt) {
    int tok = rowbase - 32 + jt * 16 + l16;
    if (tok < 0) tok = 0;             // garbage ok: masked
    const bf16* krow = qkv + (size_t)tok * QKV_LD + 512 + head * 128 + quad * 8;
    bf16x8 b0 = *reinterpret_cast<const bf16x8*>(krow);
    bf16x8 b1 = *reinterpret_cast<const bf16x8*>(krow + 32);
    sacc[jt] = __builtin_amdgcn_mfma_f32_16x16x32_bf16(aq0, b0, sacc[jt], 0, 0, 0);
    sacc[jt] = __builtin_amdgcn_mfma_f32_16x16x32_bf16(aq1, b1, sacc[jt], 0, 0, 0);
  }

  #pragma unroll
  for (int jt = 0; jt < 3; ++jt) {
    int j = jt * 16 + l16;
    #pragma unroll
    for (int r = 0; r < 4; ++r) {
      int i = quad * 4 + r;
      bool valid = (j >= i) && (j <= i + 31) && (t0 - 32 + j >= 0);
      float tau = valid ? 1.f / (1.f + __expf(-sacc[jt][r] * 0.125f)) : 0.f;
      Pl[i * 72 + j] = f2b(tau);
    }
  }
  #pragma unroll
  for (int r = 0; r < 4; ++r) Pl[(quad * 4 + r) * 72 + 48 + l16] = f2b(0.f);

  __syncthreads();   // uniform; orders LDS writes->reads across the block

  bf16x8 ap0 = *reinterpret_cast<const bf16x8*>((char*)Pl + l16 * 144 + quad * 16);
  bf16x8 ap1 = *reinterpret_cast<const bf16x8*>((char*)Pl + l16 * 144 + 64 + quad * 16);

  f32x4 macc[4] = {};
  #pragma unroll
  for (int nt = 0; nt < 4; ++nt) {
    int d = nt * 16 + l16;
    bf16x8 bv0 = *reinterpret_cast<const bf16x8*>(Vl + vt_addr(d, quad * 8));
    bf16x8 bv1 = *reinterpret_cast<const bf16x8*>(Vl + vt_addr(d, 32 + quad * 8));
    macc[nt] = __builtin_amdgcn_mfma_f32_16x16x32_bf16(ap0, bv0, macc[nt], 0, 0, 0);
    macc[nt] = __builtin_amdgcn_mfma_f32_16x16x32_bf16(ap1, bv1, macc[nt], 0, 0, 0);
  }

  // ---- vectorized output: bounce 16x64 tile through Pl region ----
  #pragma unroll
  for (int nt = 0; nt < 4; ++nt)
    #pragma unroll
    for (int r = 0; r < 4; ++r)
      Pl[(quad * 4 + r) * 72 + nt * 16 + l16] = f2b(macc[nt][r]);

  #pragma unroll
  for (int p = 0; p < 2; ++p) {
    int row = (lane >> 3) + p * 8;
    int c8  = lane & 7;
    bf16x8 ov = *reinterpret_cast<const bf16x8*>(&Pl[row * 72 + c8 * 8]);
    *reinterpret_cast<bf16x8*>(
        qkv + (size_t)(rowbase + row) * QKV_LD + head * HD_DIM + c8 * 8) = ov;
  }
}

// ---------------------------------------------------------------------------
extern "C" void kernel_launch(void* const* d_in, const int* in_sizes, int n_in,
                              void* d_out, int out_size, void* d_ws, size_t ws_size,
                              hipStream_t stream)
{
  const void* x      = d_in[0];
  const void* pre_g  = d_in[1];
  const void* pre_b  = d_in[2];
  const void* wq     = d_in[3];
  const void* wkv    = d_in[4];
  const void* wo     = d_in[5];
  const void* attn_g = d_in[6];
  const void* attn_b = d_in[7];
  const void* freqs  = d_in[8];
  const void* phases = d_in[9];
  const void* amp    = d_in[10];
  const void* w_gate = d_in[11];
  const void* w_val  = d_in[12];
  const void* w_proj = d_in[13];
  const void* ffn_g  = d_in[14];
  const void* ffn_b  = d_in[15];
  const unsigned* xdet = (const unsigned*)x;

  char* ws = (char*)d_ws;
  bf16* Btqkv = (bf16*)(ws + 512);       // 1536 x 512
  bf16* Bto   = (bf16*)(ws + 1573376);   //  512 x 512
  bf16* Btg   = (bf16*)(ws + 2097664);   // 1536 x 512
  bf16* Btv   = (bf16*)(ws + 3670528);   // 1536 x 512
  bf16* Btp   = (bf16*)(ws + 5243392);   //  512 x 1536
  bf16* h     = (bf16*)(ws + 6816256);   // 8192 x 512   (h -> s1 -> y -> u)
  bf16* qkvb  = (bf16*)(ws + 15204864);  // 8192 x 1536  (q|kv; msg in-place; then act)
  bf16* gb    = qkvb;

  // transposes + h = LN(x), fused
  prep_kernel<<<5376, 256, 0, stream>>>(
      wq, wkv, wo, w_gate, w_val, w_proj,
      Btqkv, Btqkv + 512 * 512, Bto, Btg, Btv, Btp,
      x, pre_g, pre_b, h, xdet);

  // qkv = h @ [wq|wkv]  (N=1536): 128x128 single-buffer, 8 waves, 768 blocks
  gemm_tile_kernel<128, false><<<768, 512, 0, stream>>>(h, Btqkv, qkvb, nullptr,
                                                        1536, 512, 512, 0, 12);

  // msg = window-attention (in-place over q slot)
  attn_mfma_kernel<<<1024, 256, 0, stream>>>(qkvb);

  // s1 = h + msg @ wo  (N=512): 128x64 2-buffer pipeline, 512 blocks
  gemm_tile_kernel<64, true><<<512, 512, 0, stream>>>(qkvb, Bto, h, h,
                                                      512, 512, QKV_LD, 1, 8);

  // y = LN(s1) * (1 + amp*sin(t*freqs+phases))
  ln_kernel<<<2048, 256, 0, stream>>>(h, attn_g, attn_b, h, 1,
                                      freqs, phases, amp, xdet, 0, 0);

  // act = silu(y @ w_gate) * (y @ w_val): 128x64 2-buffer, 1536 blocks
  gateval_kernel<<<1536, 512, 0, stream>>>(h, Btg, Btv, gb,
                                           1536, 512, 512, 24);

  // u = y + act @ w_proj  (N=512, K=1536): 128x64 2-buffer, 512 blocks
  gemm_tile_kernel<64, true><<<512, 512, 0, stream>>>(gb, Btp, h, h,
                                                      512, 1536, QKV_LD, 1, 8);

  // out = LN(u)
  ln_kernel<<<2048, 256, 0, stream>>>(h, ffn_g, ffn_b, d_out, 0,
                                      nullptr, nullptr, nullptr, xdet, 0, 1);
}